// Round 1
// baseline (693.263 us; speedup 1.0000x reference)
//
#include <hip/hip_runtime.h>
#include <math.h>

#define EPSV 1e-4f
#define SCHUNK 64

__device__ __forceinline__ float agent_load_f(const float* p) {
    return __hip_atomic_load(p, __ATOMIC_RELAXED, __HIP_MEMORY_SCOPE_AGENT);
}
__device__ __forceinline__ void agent_store_f(float* p, float v) {
    __hip_atomic_store(p, v, __ATOMIC_RELAXED, __HIP_MEMORY_SCOPE_AGENT);
}

// ---------------- clear: flags + ticket ----------------
__global__ void clear_kernel(int* __restrict__ flags, int n) {
    int i = blockIdx.x * blockDim.x + threadIdx.x;
    if (i < n) flags[i] = 0;
}

// ---------------- b_flat scan: 1024 elements/block (unchanged) ----------------
__global__ void scan_sum_kernel(const int* __restrict__ b, int n,
                                int* __restrict__ bsum) {
    __shared__ int red[256];
    int tid = threadIdx.x;
    int base = blockIdx.x * 1024 + tid * 4;
    int s = 0;
#pragma unroll
    for (int k = 0; k < 4; ++k) {
        int j = base + k;
        if (j < n) s += b[j];
    }
    red[tid] = s;
    __syncthreads();
    for (int off = 128; off > 0; off >>= 1) {
        if (tid < off) red[tid] += red[tid + off];
        __syncthreads();
    }
    if (tid == 0) bsum[blockIdx.x] = red[0];
}

__global__ void scan_offsets_kernel(const int* __restrict__ bsum,
                                    int* __restrict__ boff, int nb) {
    __shared__ int sh[1024];
    int i = threadIdx.x;
    int v = (i < nb) ? bsum[i] : 0;
    sh[i] = v;
    __syncthreads();
    for (int off = 1; off < 1024; off <<= 1) {
        int t = sh[i];
        if (i >= off) t += sh[i - off];
        __syncthreads();
        sh[i] = t;
        __syncthreads();
    }
    if (i < nb) boff[i] = sh[i] - v;
}

__global__ void scan_emit_kernel(const int* __restrict__ b, int n,
                                 const int* __restrict__ boff,
                                 int* __restrict__ sidx, int L, int Louter) {
    __shared__ int red[256];
    int tid = threadIdx.x;
    int base = blockIdx.x * 1024 + tid * 4;
    int v[4];
    int s = 0;
#pragma unroll
    for (int k = 0; k < 4; ++k) {
        int j = base + k;
        v[k] = (j < n) ? b[j] : 0;
        s += v[k];
    }
    red[tid] = s;
    __syncthreads();
    for (int off = 1; off < 256; off <<= 1) {
        int t = red[tid];
        if (tid >= off) t += red[tid - off];
        __syncthreads();
        red[tid] = t;
        __syncthreads();
    }
    int cum = red[tid] - s + boff[blockIdx.x];
#pragma unroll
    for (int k = 0; k < 4; ++k) {
        int j = base + k;
        if (j < n) {
            cum += v[k];
            if (v[k] > 0) {
                int t = cum - 1;
                if (t >= 0 && t < L) sidx[t] = j;
            }
        }
    }
    if (base == 0 && blockIdx.x == 0) sidx[L] = Louter;
}

// ---------------- single-pass decoupled-lookback scan + scatter ----------------
// blockDim.x == d (512). One channel per thread. CHUNK=64 timesteps per block.
// z[t] (zero-init local scan) kept in 64 VGPRs; aggregate (E,P) published with
// device-scope atomics; lookback walks aggregates only (no inclusive stage
// needed: prodAcc underflows to 0.0f after ~2 chunks for this data, and seq
// resets make P exactly 0). Deadlock-free: aggregates are published before any
// wait, and the ticket guarantees predecessors are resident.
__global__ __launch_bounds__(512) void scan_lookback_kernel(
        const float* __restrict__ h,
        const float* __restrict__ psel,
        const int* __restrict__ seq,
        const int* __restrict__ sidx,
        float* __restrict__ out,
        float* __restrict__ aggE,   // [NC][d]
        float* __restrict__ aggP,   // [NC]
        int* __restrict__ flags,    // [NC] flags, flags[NC] = ticket
        int L, int d, int Louter, int NC) {
    __shared__ float sh_a[SCHUNK];
    __shared__ float sh_p[SCHUNK];
    __shared__ float sh_A[SCHUNK];
    __shared__ int   sh_j[SCHUNK + 1];
    __shared__ int   sh_g;

    const int tid = threadIdx.x;
    if (tid == 0) sh_g = atomicAdd(&flags[NC], 1);  // device-scope ticket
    __syncthreads();
    const int g  = sh_g;
    const int t0 = g * SCHUNK;
    const int nt = min(SCHUNK, L - t0);

    // prologue: per-timestep scalars (fused prep) + scatter ranges into LDS
    if (tid < nt) {
        int t = t0 + tid;
        float p = psel[t];
        p = fminf(fmaxf(p, EPSV), 1.0f - EPSV);
        bool start = (t == 0) || (seq[t] != seq[t - 1]);
        sh_a[tid] = start ? 0.0f : (1.0f - p);   // exp(-dt) == 1-p exactly
        sh_p[tid] = p;                           // b_t = p*h
    }
    if (tid <= nt) sh_j[tid] = sidx[t0 + tid];   // sidx[L] sentinel exists
    __syncthreads();
    if (tid < nt) {                              // A_t = prod_{u<=t} a_u
        float prod = 1.0f;
        for (int u = 0; u <= tid; ++u) prod *= sh_a[u];
        sh_A[tid] = prod;
    }
    __syncthreads();

    const int c = tid;
    const float* __restrict__ hp = h + (size_t)t0 * d + c;

    // ---- pass 1: zero-init local scan, z in registers ----
    float z[SCHUNK];
    float st = 0.0f;
    const bool full = (nt == SCHUNK);
    if (full) {
#pragma unroll
        for (int grp = 0; grp < SCHUNK / 8; ++grp) {
            float hb[8];
#pragma unroll
            for (int k = 0; k < 8; ++k)
                hb[k] = __builtin_nontemporal_load(hp + (size_t)(grp * 8 + k) * d);
#pragma unroll
            for (int k = 0; k < 8; ++k) {
                int t = grp * 8 + k;
                st = fmaf(sh_a[t], st, sh_p[t] * hb[k]);
                z[t] = st;
            }
        }
    } else {
        for (int t = 0; t < nt; ++t) {
            float hv = hp[(size_t)t * d];
            st = fmaf(sh_a[t], st, sh_p[t] * hv);
        }
    }

    // ---- publish aggregate (before any waiting -> no deadlock) ----
    agent_store_f(&aggE[(size_t)g * d + c], st);
    float P = (nt > 0) ? sh_A[nt - 1] : 1.0f;
    __syncthreads();            // drains vmcnt(0): all aggE stores complete
    if (tid == 0) {
        agent_store_f(&aggP[g], P);
        __threadfence();
        __hip_atomic_store(&flags[g], 1, __ATOMIC_RELEASE, __HIP_MEMORY_SCOPE_AGENT);
    }

    // ---- decoupled lookback: carry = state at end of chunk g-1 ----
    float carry = 0.0f;
    float prodAcc = 1.0f;
    for (int i = g - 1; i >= 0; --i) {
        while (__hip_atomic_load(&flags[i], __ATOMIC_ACQUIRE,
                                 __HIP_MEMORY_SCOPE_AGENT) == 0) {
            __builtin_amdgcn_s_sleep(8);
        }
        carry = fmaf(prodAcc, agent_load_f(&aggE[(size_t)i * d + c]), carry);
        prodAcc *= agent_load_f(&aggP[i]);
        if (prodAcc == 0.0f) break;   // decay product underflow / seq reset
    }

    // ---- pass 2: finalize y_t = A_t*carry + z_t, scatter to out ----
    if (full) {
#pragma unroll
        for (int t = 0; t < SCHUNK; ++t) {
            float y = fmaf(sh_A[t], carry, z[t]);
            int j0 = max(sh_j[t], 0);
            int j1 = min(sh_j[t + 1], Louter);
            for (int j = j0; j < j1; ++j)
                __builtin_nontemporal_store(y, out + (size_t)j * d + c);
        }
    } else {
        // tail chunk: rescan with carry folded in (h is cache-hot)
        float s2 = carry;
        for (int t = 0; t < nt; ++t) {
            float hv = hp[(size_t)t * d];
            s2 = fmaf(sh_a[t], s2, sh_p[t] * hv);
            int j0 = max(sh_j[t], 0);
            int j1 = min(sh_j[t + 1], Louter);
            for (int j = j0; j < j1; ++j)
                out[(size_t)j * d + c] = s2;
        }
    }
}

extern "C" void kernel_launch(void* const* d_in, const int* in_sizes, int n_in,
                              void* d_out, int out_size, void* d_ws, size_t ws_size,
                              hipStream_t stream) {
    const float* h     = (const float*)d_in[0];
    const int*   bflat = (const int*)d_in[1];
    const float* psel  = (const float*)d_in[2];
    const int*   seq   = (const int*)d_in[3];
    float* out = (float*)d_out;

    const int L      = in_sizes[2];          // 131072
    const int Louter = in_sizes[1];          // 262144
    const int d      = in_sizes[0] / L;      // 512

    const int NC = (L + SCHUNK - 1) / SCHUNK;   // 2048
    const int nb = (Louter + 1023) / 1024;      // 256 scan blocks

    // workspace layout (256B-aligned slices) — total ~4.6 MB
    char* ws = (char*)d_ws;
    size_t off = 0;
    auto alloc = [&](size_t bytes) -> void* {
        void* p = ws + off;
        off = (off + bytes + 255) & ~(size_t)255;
        return p;
    };
    float* aggE  = (float*)alloc((size_t)NC * d * 4);
    float* aggP  = (float*)alloc((size_t)NC * 4);
    int*   flags = (int*)alloc((size_t)(NC + 1) * 4);   // +1 = ticket
    int*   bsum  = (int*)alloc((size_t)nb * 4);
    int*   boff  = (int*)alloc((size_t)nb * 4);
    int*   sidx  = (int*)alloc((size_t)(L + 1) * 4);
    (void)ws_size;

    clear_kernel<<<(NC + 1 + 255) / 256, 256, 0, stream>>>(flags, NC + 1);

    scan_sum_kernel<<<nb, 256, 0, stream>>>(bflat, Louter, bsum);
    scan_offsets_kernel<<<1, 1024, 0, stream>>>(bsum, boff, nb);
    scan_emit_kernel<<<nb, 256, 0, stream>>>(bflat, Louter, boff, sidx, L, Louter);

    scan_lookback_kernel<<<NC, d, 0, stream>>>(h, psel, seq, sidx, out,
                                               aggE, aggP, flags,
                                               L, d, Louter, NC);
}

// Round 2
// 190.020 us; speedup vs baseline: 3.6484x; 3.6484x over previous
//
#include <hip/hip_runtime.h>
#include <math.h>

#define EPSV 1e-4f
#define SCHUNK 64

// Relaxed agent-scope atomics: compile to point-wise LLC-coherent loads/stores
// (sc1) with NO cache-wide invalidate/writeback (unlike acquire/release, which
// emit buffer_inv / buffer_wbl2 on gfx950 because per-XCD L2s are non-coherent).
__device__ __forceinline__ float agent_load_f(const float* p) {
    return __hip_atomic_load(p, __ATOMIC_RELAXED, __HIP_MEMORY_SCOPE_AGENT);
}
__device__ __forceinline__ void agent_store_f(float* p, float v) {
    __hip_atomic_store(p, v, __ATOMIC_RELAXED, __HIP_MEMORY_SCOPE_AGENT);
}
__device__ __forceinline__ int agent_load_i(const int* p) {
    return __hip_atomic_load(p, __ATOMIC_RELAXED, __HIP_MEMORY_SCOPE_AGENT);
}
__device__ __forceinline__ void agent_store_i(int* p, int v) {
    __hip_atomic_store(p, v, __ATOMIC_RELAXED, __HIP_MEMORY_SCOPE_AGENT);
}

// ---------------- clear: flags + ticket ----------------
__global__ void clear_kernel(int* __restrict__ flags, int n) {
    int i = blockIdx.x * blockDim.x + threadIdx.x;
    if (i < n) flags[i] = 0;
}

// ---------------- b_flat scan: 1024 elements/block ----------------
__global__ void scan_sum_kernel(const int* __restrict__ b, int n,
                                int* __restrict__ bsum) {
    __shared__ int red[256];
    int tid = threadIdx.x;
    int base = blockIdx.x * 1024 + tid * 4;
    int s = 0;
#pragma unroll
    for (int k = 0; k < 4; ++k) {
        int j = base + k;
        if (j < n) s += b[j];
    }
    red[tid] = s;
    __syncthreads();
    for (int off = 128; off > 0; off >>= 1) {
        if (tid < off) red[tid] += red[tid + off];
        __syncthreads();
    }
    if (tid == 0) bsum[blockIdx.x] = red[0];
}

__global__ void scan_offsets_kernel(const int* __restrict__ bsum,
                                    int* __restrict__ boff, int nb) {
    __shared__ int sh[1024];
    int i = threadIdx.x;
    int v = (i < nb) ? bsum[i] : 0;
    sh[i] = v;
    __syncthreads();
    for (int off = 1; off < 1024; off <<= 1) {
        int t = sh[i];
        if (i >= off) t += sh[i - off];
        __syncthreads();
        sh[i] = t;
        __syncthreads();
    }
    if (i < nb) boff[i] = sh[i] - v;
}

__global__ void scan_emit_kernel(const int* __restrict__ b, int n,
                                 const int* __restrict__ boff,
                                 int* __restrict__ sidx, int L, int Louter) {
    __shared__ int red[256];
    int tid = threadIdx.x;
    int base = blockIdx.x * 1024 + tid * 4;
    int v[4];
    int s = 0;
#pragma unroll
    for (int k = 0; k < 4; ++k) {
        int j = base + k;
        v[k] = (j < n) ? b[j] : 0;
        s += v[k];
    }
    red[tid] = s;
    __syncthreads();
    for (int off = 1; off < 256; off <<= 1) {
        int t = red[tid];
        if (tid >= off) t += red[tid - off];
        __syncthreads();
        red[tid] = t;
        __syncthreads();
    }
    int cum = red[tid] - s + boff[blockIdx.x];
#pragma unroll
    for (int k = 0; k < 4; ++k) {
        int j = base + k;
        if (j < n) {
            cum += v[k];
            if (v[k] > 0) {
                int t = cum - 1;
                if (t >= 0 && t < L) sidx[t] = j;
            }
        }
    }
    if (base == 0 && blockIdx.x == 0) sidx[L] = Louter;
}

// ---------------- single-pass decoupled-lookback scan + scatter ----------------
// blockDim.x == d (512), one channel/thread, SCHUNK=64 timesteps per block.
// Pass 1 computes only the chunk aggregate (no z[] array -> no spill).
// Pass 2 re-reads h (L2/LLC-hot: just read, and no cache invalidations anywhere)
// and rescans with the carry folded in, scattering directly to out.
// Communication: relaxed agent atomics + waitcnt ordering. Thread 0 alone spins.
// Deadlock-free: ticket => predecessors resident; flags published before any wait.
__global__ __launch_bounds__(512, 4) void scan_lookback_kernel(
        const float* __restrict__ h,
        const float* __restrict__ psel,
        const int* __restrict__ seq,
        const int* __restrict__ sidx,
        float* __restrict__ out,
        float* __restrict__ aggE,   // [NC][d]
        float* __restrict__ aggP,   // [NC]
        int* __restrict__ flags,    // [NC] flags, flags[NC] = ticket
        int L, int d, int Louter, int NC) {
    __shared__ float sh_a[SCHUNK];
    __shared__ float sh_p[SCHUNK];
    __shared__ int   sh_j[SCHUNK + 1];
    __shared__ int   sh_g;
    __shared__ float sh_Pown;
    __shared__ float sh_Pbr;

    const int tid = threadIdx.x;
    if (tid == 0) sh_g = atomicAdd(&flags[NC], 1);  // device-scope ticket
    __syncthreads();
    const int g  = sh_g;
    const int t0 = g * SCHUNK;
    const int nt = min(SCHUNK, L - t0);

    // prologue: per-timestep scalars (fused prep) + scatter ranges into LDS
    if (tid < nt) {
        int t = t0 + tid;
        float p = psel[t];
        p = fminf(fmaxf(p, EPSV), 1.0f - EPSV);
        bool start = (t == 0) || (seq[t] != seq[t - 1]);
        sh_a[tid] = start ? 0.0f : (1.0f - p);   // exp(-dt) == 1-p exactly
        sh_p[tid] = p;                           // b_t = p*h
    }
    if (tid <= nt) sh_j[tid] = sidx[t0 + tid];   // sidx[L] sentinel exists
    __syncthreads();

    // chunk decay product P = prod(a) via wave-0 butterfly (no serial chain)
    if (tid < 64) {
        float v = (tid < nt) ? sh_a[tid] : 1.0f;
#pragma unroll
        for (int m = 1; m < 64; m <<= 1) v *= __shfl_xor(v, m);
        if (tid == 0) sh_Pown = v;
    }

    const int c = tid;
    const float* __restrict__ hp = h + (size_t)t0 * d + c;

    // ---- pass 1: aggregate-only local scan (zero init) ----
    float st = 0.0f;
    const bool full = (nt == SCHUNK);
    if (full) {
#pragma unroll
        for (int grp = 0; grp < SCHUNK / 8; ++grp) {
            float hb[8];
#pragma unroll
            for (int k = 0; k < 8; ++k)
                hb[k] = hp[(size_t)(grp * 8 + k) * d];   // cacheable: reused in pass 2
#pragma unroll
            for (int k = 0; k < 8; ++k) {
                int t = grp * 8 + k;
                st = fmaf(sh_a[t], st, sh_p[t] * hb[k]);
            }
        }
    } else {
        for (int t = 0; t < nt; ++t)
            st = fmaf(sh_a[t], st, sh_p[t] * hp[(size_t)t * d]);
    }

    // ---- publish aggregate (relaxed + waitcnt ordering; no cache-wide ops) ----
    agent_store_f(&aggE[(size_t)g * d + c], st);
    __syncthreads();            // drains vmcnt(0): all aggE stores complete
    if (tid == 0) {
        agent_store_f(&aggP[g], sh_Pown);
        asm volatile("s_waitcnt vmcnt(0)" ::: "memory");  // aggP visible before flag
        agent_store_i(&flags[g], 1);
    }

    // ---- decoupled lookback: carry = state at end of chunk g-1 ----
    // Thread 0 alone spins (relaxed); data loads only after flag observed.
    float carry = 0.0f;
    float prodAcc = 1.0f;
    for (int i = g - 1; i >= 0; --i) {
        if (tid == 0) {
            while (agent_load_i(&flags[i]) == 0) __builtin_amdgcn_s_sleep(1);
            sh_Pbr = agent_load_f(&aggP[i]);
        }
        __syncthreads();
        float Pi = sh_Pbr;
        carry = fmaf(prodAcc, agent_load_f(&aggE[(size_t)i * d + c]), carry);
        prodAcc *= Pi;                    // uniform across threads
        __syncthreads();                  // sh_Pbr reused next iteration
        if (prodAcc == 0.0f) break;       // decay underflow / seq reset (~2 steps)
    }

    // ---- pass 2: rescan with carry folded in, scatter to out ----
    float s2 = carry;
    if (full) {
#pragma unroll
        for (int grp = 0; grp < SCHUNK / 8; ++grp) {
            float hb[8];
#pragma unroll
            for (int k = 0; k < 8; ++k)
                hb[k] = hp[(size_t)(grp * 8 + k) * d];   // L2/LLC hit
#pragma unroll
            for (int k = 0; k < 8; ++k) {
                int t = grp * 8 + k;
                s2 = fmaf(sh_a[t], s2, sh_p[t] * hb[k]);
                int j0 = max(sh_j[t], 0);
                int j1 = min(sh_j[t + 1], Louter);
                for (int j = j0; j < j1; ++j)
                    __builtin_nontemporal_store(s2, out + (size_t)j * d + c);
            }
        }
    } else {
        for (int t = 0; t < nt; ++t) {
            s2 = fmaf(sh_a[t], s2, sh_p[t] * hp[(size_t)t * d]);
            int j0 = max(sh_j[t], 0);
            int j1 = min(sh_j[t + 1], Louter);
            for (int j = j0; j < j1; ++j)
                out[(size_t)j * d + c] = s2;
        }
    }
}

extern "C" void kernel_launch(void* const* d_in, const int* in_sizes, int n_in,
                              void* d_out, int out_size, void* d_ws, size_t ws_size,
                              hipStream_t stream) {
    const float* h     = (const float*)d_in[0];
    const int*   bflat = (const int*)d_in[1];
    const float* psel  = (const float*)d_in[2];
    const int*   seq   = (const int*)d_in[3];
    float* out = (float*)d_out;

    const int L      = in_sizes[2];          // 131072
    const int Louter = in_sizes[1];          // 262144
    const int d      = in_sizes[0] / L;      // 512

    const int NC = (L + SCHUNK - 1) / SCHUNK;   // 2048
    const int nb = (Louter + 1023) / 1024;      // 256 scan blocks

    // workspace layout (256B-aligned slices) — total ~4.6 MB
    char* ws = (char*)d_ws;
    size_t off = 0;
    auto alloc = [&](size_t bytes) -> void* {
        void* p = ws + off;
        off = (off + bytes + 255) & ~(size_t)255;
        return p;
    };
    float* aggE  = (float*)alloc((size_t)NC * d * 4);
    float* aggP  = (float*)alloc((size_t)NC * 4);
    int*   flags = (int*)alloc((size_t)(NC + 1) * 4);   // +1 = ticket
    int*   bsum  = (int*)alloc((size_t)nb * 4);
    int*   boff  = (int*)alloc((size_t)nb * 4);
    int*   sidx  = (int*)alloc((size_t)(L + 1) * 4);
    (void)ws_size;

    clear_kernel<<<(NC + 1 + 255) / 256, 256, 0, stream>>>(flags, NC + 1);

    scan_sum_kernel<<<nb, 256, 0, stream>>>(bflat, Louter, bsum);
    scan_offsets_kernel<<<1, 1024, 0, stream>>>(bsum, boff, nb);
    scan_emit_kernel<<<nb, 256, 0, stream>>>(bflat, Louter, boff, sidx, L, Louter);

    scan_lookback_kernel<<<NC, d, 0, stream>>>(h, psel, seq, sidx, out,
                                               aggE, aggP, flags,
                                               L, d, Louter, NC);
}